// Round 1
// baseline (86.470 us; speedup 1.0000x reference)
//
#include <hip/hip_runtime.h>

// y[n][r] = sum_c weights[weight_idx[n]][r][c] * values[input_idx[n]][c]
// N=2M, M=2M, U=1024, R=C=8. All f32.
// Memory-bound: ~144 MB essential HBM traffic. Weights (256 KB) are L2-resident.

__global__ __launch_bounds__(256) void neuron_gemv_kernel(
    const float4* __restrict__ values,   // [M][2] as float4
    const float4* __restrict__ weights,  // [U][16] as float4
    const int*    __restrict__ input_idx,
    const int*    __restrict__ weight_idx,
    float4*       __restrict__ out,      // [N][2] as float4
    int N)
{
    int n = blockIdx.x * blockDim.x + threadIdx.x;
    if (n >= N) return;

    int ii = input_idx[n];
    int wi = weight_idx[n];

    // Gather input row (32 B)
    float4 x0 = values[(size_t)ii * 2 + 0];
    float4 x1 = values[(size_t)ii * 2 + 1];

    // Weight matrix base (256 B, L2-hot)
    const float4* w = weights + (size_t)wi * 16;

    float y[8];
#pragma unroll
    for (int r = 0; r < 8; ++r) {
        float4 w0 = w[r * 2 + 0];
        float4 w1 = w[r * 2 + 1];
        y[r] = w0.x * x0.x + w0.y * x0.y + w0.z * x0.z + w0.w * x0.w
             + w1.x * x1.x + w1.y * x1.y + w1.z * x1.z + w1.w * x1.w;
    }

    float4 o0 = make_float4(y[0], y[1], y[2], y[3]);
    float4 o1 = make_float4(y[4], y[5], y[6], y[7]);
    out[(size_t)n * 2 + 0] = o0;
    out[(size_t)n * 2 + 1] = o1;
}

extern "C" void kernel_launch(void* const* d_in, const int* in_sizes, int n_in,
                              void* d_out, int out_size, void* d_ws, size_t ws_size,
                              hipStream_t stream) {
    const float4* values  = (const float4*)d_in[0];
    const float4* weights = (const float4*)d_in[1];
    const int*    iidx    = (const int*)d_in[2];
    const int*    widx    = (const int*)d_in[3];
    float4*       out     = (float4*)d_out;

    int N = in_sizes[2];  // input_idx element count

    const int block = 256;
    const int grid  = (N + block - 1) / block;
    neuron_gemv_kernel<<<grid, block, 0, stream>>>(values, weights, iidx, widx, out, N);
}